// Round 4
// baseline (245.640 us; speedup 1.0000x reference)
//
#include <hip/hip_runtime.h>

#define F_IN 128
#define HID 64
#define CLS 32
#define CAP 64           // per-node CSR window (deg ~ Poisson(16); P(>=64) ~ 2e-18, write-guarded)

typedef short v8s __attribute__((ext_vector_type(8)));
typedef float f4 __attribute__((ext_vector_type(4)));
typedef float f2 __attribute__((ext_vector_type(2)));

// ---- helpers ----
__device__ __forceinline__ float bflo(unsigned int w) { return __uint_as_float(w << 16); }
__device__ __forceinline__ float bfhi(unsigned int w) { return __uint_as_float(w & 0xFFFF0000u); }
__device__ __forceinline__ unsigned short f2bf(float f) {
    unsigned int u = __float_as_uint(f);
    u += 0x7FFFu + ((u >> 16) & 1u);
    return (unsigned short)(u >> 16);
}
// single-instruction RNE pack of 2 f32 -> 2 bf16
__device__ __forceinline__ unsigned int pack2(float lo, float hi) {
    unsigned int r;
    asm("v_cvt_pk_bf16_f32 %0, %1, %2" : "=v"(r) : "v"(lo), "v"(hi));
    return r;
}
__device__ __forceinline__ unsigned char f2fp8(float v) {
    return (unsigned char)(__builtin_amdgcn_cvt_pk_fp8_f32(v, v, 0, false) & 0xFF);
}

// ============ K1: FRONT = atomic CSR scatter (blocks [0,sB)) || GEMM1 (blocks [sB,..)) ====
// Scatter: one global atomic per edge gives the CSR slot directly (fixed 64-slot windows,
// no histogram, no prefix scan, no intermediate buffer). GEMM1 stores UNNORMALIZED fp8
// (dinv applied per-edge in the gather; fp8 relative error is scale-invariant).
__global__ __launch_bounds__(256) void k_front(const int* __restrict__ src,
                                               const int* __restrict__ dst,
                                               int* __restrict__ deg,
                                               int* __restrict__ csr,
                                               const float* __restrict__ x,
                                               const float* __restrict__ W1,
                                               unsigned char* __restrict__ y,
                                               int E, int n, int sB) {
    __shared__ unsigned short w1[HID * 136];
    int tid = threadIdx.x;
    int bid = blockIdx.x;

    if (bid < sB) {
        // ---- CSR scatter: chunk = bid (2048 edges) ----
        int e0 = bid << 11;
#pragma unroll
        for (int k = 0; k < 8; ++k) {
            int e = e0 + k * 256 + tid;
            if (e < E) {
                int d = dst[e];
                int rnk = atomicAdd(&deg[d], 1);
                if (rnk < CAP) csr[(d << 6) + rnk] = src[e];
            }
        }
    } else {
        // ---- GEMM1: x[N,128] @ W1[128,64] -> fp8 y[N,64] (unnormalized) ----
        for (int i = tid; i < F_IN * HID; i += 256) {
            int k = i >> 6, nn = i & 63;
            w1[nn * 136 + k] = f2bf(W1[i]);
        }
        __syncthreads();
        int lane = tid & 63;
        int quad = lane >> 4, c = lane & 15;
        int nstripes = (n + 15) >> 4;
        int stripe = (bid - sB) * 4 + (tid >> 6);
        if (stripe >= nstripes) return;
        int row0 = stripe << 4;

        f4 acc[4] = {};
        union { unsigned int u[4]; v8s v; } au;
#pragma unroll
        for (int ks = 0; ks < 4; ++ks) {
            int k0 = ks * 32 + quad * 8;
            int row = row0 + c;
            if (row >= n) row = n - 1;
            const float* xp = x + (size_t)row * F_IN + k0;
            float4 lo = *(const float4*)xp;
            float4 hi = *(const float4*)(xp + 4);
            au.u[0] = pack2(lo.x, lo.y);
            au.u[1] = pack2(lo.z, lo.w);
            au.u[2] = pack2(hi.x, hi.y);
            au.u[3] = pack2(hi.z, hi.w);
            v8s a = au.v;
#pragma unroll
            for (int nt = 0; nt < 4; ++nt) {
                v8s bb = *(const v8s*)&w1[(nt * 16 + c) * 136 + k0];
                acc[nt] = __builtin_amdgcn_mfma_f32_16x16x32_bf16(a, bb, acc[nt], 0, 0, 0);
            }
        }
#pragma unroll
        for (int reg = 0; reg < 4; ++reg) {
            int row = row0 + quad * 4 + reg;
            if (row < n) {
#pragma unroll
                for (int nt = 0; nt < 4; ++nt)
                    y[(size_t)row * HID + nt * 16 + c] = f2fp8(acc[nt][reg]);
            }
        }
    }
}

// ============ K2: gather64 (fp8, per-edge rsqrt(deg[src]+1)) + bias + relu + W2 -> bf16 y2 ====
// 8 lanes per node (uint2 fp8 loads), 32 nodes/block; h tile staged in LDS, then the
// proven gemm2 MFMA fragment pattern runs on the LDS tile.
__global__ __launch_bounds__(256) void k_gather64_w2(const int* __restrict__ deg,
                                                     const int* __restrict__ csr,
                                                     const unsigned char* __restrict__ xw8,
                                                     const float* __restrict__ b1,
                                                     const float* __restrict__ W2,
                                                     unsigned short* __restrict__ y2, int n) {
    __shared__ unsigned short Wt[CLS * 72];   // W2 staged as [n][k], padded
    __shared__ unsigned short Hl[32 * 72];    // relu(h) tile, bf16, padded rows
    int tid = threadIdx.x;
    for (int i = tid; i < HID * CLS; i += 256) {
        int k = i >> 5, nn = i & 31;
        Wt[nn * 72 + k] = f2bf(W2[i]);
    }
    // (Wt only read after the barrier below -> no extra barrier needed)

    int g = tid >> 3;                 // local node 0..31
    int l = tid & 7;                  // fp8 cols 8l..8l+7
    int node = blockIdx.x * 32 + g;

    if (node < n) {
        int cnt_t = deg[node];
        float dd = rsqrtf((float)(cnt_t + 1));
        int cntv = (cnt_t < CAP) ? cnt_t : CAP;
        int p0 = node << 6;
        int p1 = p0 + cntv;
        uint2 sw = *(const uint2*)(xw8 + (size_t)node * HID + l * 8);

        f2 a0 = {0.f, 0.f}, a1 = a0, a2 = a0, a3 = a0;
        f2 c0 = a0, c1 = a0, c2 = a0, c3 = a0;
        int q = p0;
        for (; q + 3 < p1; q += 4) {
            int s0 = csr[q], s1 = csr[q + 1], s2 = csr[q + 2], s3 = csr[q + 3];
            float d0 = rsqrtf((float)(deg[s0] + 1));
            float d1 = rsqrtf((float)(deg[s1] + 1));
            float d2 = rsqrtf((float)(deg[s2] + 1));
            float d3 = rsqrtf((float)(deg[s3] + 1));
            uint2 w0 = *(const uint2*)(xw8 + (size_t)s0 * HID + l * 8);
            uint2 w1 = *(const uint2*)(xw8 + (size_t)s1 * HID + l * 8);
            uint2 w2 = *(const uint2*)(xw8 + (size_t)s2 * HID + l * 8);
            uint2 w3 = *(const uint2*)(xw8 + (size_t)s3 * HID + l * 8);
            f2 D0 = {d0, d0}, D1 = {d1, d1}, D2 = {d2, d2}, D3 = {d3, d3};
            a0 += __builtin_amdgcn_cvt_pk_f32_fp8(w0.x, false) * D0;
            a1 += __builtin_amdgcn_cvt_pk_f32_fp8(w0.x, true) * D0;
            a2 += __builtin_amdgcn_cvt_pk_f32_fp8(w0.y, false) * D0;
            a3 += __builtin_amdgcn_cvt_pk_f32_fp8(w0.y, true) * D0;
            c0 += __builtin_amdgcn_cvt_pk_f32_fp8(w1.x, false) * D1;
            c1 += __builtin_amdgcn_cvt_pk_f32_fp8(w1.x, true) * D1;
            c2 += __builtin_amdgcn_cvt_pk_f32_fp8(w1.y, false) * D1;
            c3 += __builtin_amdgcn_cvt_pk_f32_fp8(w1.y, true) * D1;
            a0 += __builtin_amdgcn_cvt_pk_f32_fp8(w2.x, false) * D2;
            a1 += __builtin_amdgcn_cvt_pk_f32_fp8(w2.x, true) * D2;
            a2 += __builtin_amdgcn_cvt_pk_f32_fp8(w2.y, false) * D2;
            a3 += __builtin_amdgcn_cvt_pk_f32_fp8(w2.y, true) * D2;
            c0 += __builtin_amdgcn_cvt_pk_f32_fp8(w3.x, false) * D3;
            c1 += __builtin_amdgcn_cvt_pk_f32_fp8(w3.x, true) * D3;
            c2 += __builtin_amdgcn_cvt_pk_f32_fp8(w3.y, false) * D3;
            c3 += __builtin_amdgcn_cvt_pk_f32_fp8(w3.y, true) * D3;
        }
        for (; q < p1; ++q) {
            int s0 = csr[q];
            float d0 = rsqrtf((float)(deg[s0] + 1));
            uint2 w0 = *(const uint2*)(xw8 + (size_t)s0 * HID + l * 8);
            f2 D0 = {d0, d0};
            a0 += __builtin_amdgcn_cvt_pk_f32_fp8(w0.x, false) * D0;
            a1 += __builtin_amdgcn_cvt_pk_f32_fp8(w0.x, true) * D0;
            a2 += __builtin_amdgcn_cvt_pk_f32_fp8(w0.y, false) * D0;
            a3 += __builtin_amdgcn_cvt_pk_f32_fp8(w0.y, true) * D0;
        }
        a0 += c0; a1 += c1; a2 += c2; a3 += c3;
        f2 DS = {dd, dd};
        a0 += __builtin_amdgcn_cvt_pk_f32_fp8(sw.x, false) * DS;
        a1 += __builtin_amdgcn_cvt_pk_f32_fp8(sw.x, true) * DS;
        a2 += __builtin_amdgcn_cvt_pk_f32_fp8(sw.y, false) * DS;
        a3 += __builtin_amdgcn_cvt_pk_f32_fp8(sw.y, true) * DS;

        float4 bb0 = *(const float4*)(b1 + l * 8);
        float4 bb1 = *(const float4*)(b1 + l * 8 + 4);
        float h0 = fmaxf(a0.x * dd + bb0.x, 0.f);
        float h1 = fmaxf(a0.y * dd + bb0.y, 0.f);
        float h2 = fmaxf(a1.x * dd + bb0.z, 0.f);
        float h3 = fmaxf(a1.y * dd + bb0.w, 0.f);
        float h4 = fmaxf(a2.x * dd + bb1.x, 0.f);
        float h5 = fmaxf(a2.y * dd + bb1.y, 0.f);
        float h6 = fmaxf(a3.x * dd + bb1.z, 0.f);
        float h7 = fmaxf(a3.y * dd + bb1.w, 0.f);
        uint4 hp;
        hp.x = pack2(h0, h1);
        hp.y = pack2(h2, h3);
        hp.z = pack2(h4, h5);
        hp.w = pack2(h6, h7);
        *(uint4*)&Hl[g * 72 + l * 8] = hp;
    }
    __syncthreads();

    // ---- MFMA epilogue: 4 waves, wave wv handles row-tile t=wv&1, col-tile nt=wv>>1 ----
    int wv = tid >> 6;
    int t = wv & 1, nt = wv >> 1;
    int lane = tid & 63, quad = lane >> 4, c = lane & 15;
    f4 acc = {};
#pragma unroll
    for (int ks = 0; ks < 2; ++ks) {
        int k0 = ks * 32 + quad * 8;
        v8s aF = *(const v8s*)&Hl[(t * 16 + c) * 72 + k0];
        v8s bF = *(const v8s*)&Wt[(nt * 16 + c) * 72 + k0];
        acc = __builtin_amdgcn_mfma_f32_16x16x32_bf16(aF, bF, acc, 0, 0, 0);
    }
    int row0 = blockIdx.x * 32 + t * 16;
#pragma unroll
    for (int reg = 0; reg < 4; ++reg) {
        int row = row0 + quad * 4 + reg;
        if (row < n) {
            float dd2 = rsqrtf((float)(deg[row] + 1));
            y2[(size_t)row * CLS + nt * 16 + c] = f2bf(acc[reg] * dd2);
        }
    }
}

// ============ K3: gather width 32 (bf16 rows) + log_softmax: 4 lanes/node, uint4 loads ====
__global__ __launch_bounds__(256) void k_gather32_lsm(const int* __restrict__ deg,
                                                      const int* __restrict__ csr,
                                                      const unsigned short* __restrict__ hwb,
                                                      const float* __restrict__ b,
                                                      float* __restrict__ out, int n) {
    int tid = threadIdx.x;
    int node = blockIdx.x * 64 + (tid >> 2);
    if (node >= n) return;
    int l = tid & 3;    // bf16 cols 8l..8l+7
    int cnt_t = deg[node];
    float dd = rsqrtf((float)(cnt_t + 1));
    int cntv = (cnt_t < CAP) ? cnt_t : CAP;
    int p0 = node << 6;
    int p1 = p0 + cntv;
    uint4 sw = *(const uint4*)(hwb + (size_t)node * CLS + l * 8);

    float A0 = 0.f, A1 = 0.f, A2 = 0.f, A3 = 0.f, A4 = 0.f, A5 = 0.f, A6 = 0.f, A7 = 0.f;
    float B0 = 0.f, B1 = 0.f, B2 = 0.f, B3 = 0.f, B4 = 0.f, B5 = 0.f, B6 = 0.f, B7 = 0.f;
    int p = p0;
    for (; p + 3 < p1; p += 4) {
        int s0 = csr[p], s1 = csr[p + 1], s2 = csr[p + 2], s3 = csr[p + 3];
        uint4 w0 = *(const uint4*)(hwb + (size_t)s0 * CLS + l * 8);
        uint4 w1 = *(const uint4*)(hwb + (size_t)s1 * CLS + l * 8);
        uint4 w2 = *(const uint4*)(hwb + (size_t)s2 * CLS + l * 8);
        uint4 w3 = *(const uint4*)(hwb + (size_t)s3 * CLS + l * 8);
        A0 += bflo(w0.x); A1 += bfhi(w0.x); A2 += bflo(w0.y); A3 += bfhi(w0.y);
        A4 += bflo(w0.z); A5 += bfhi(w0.z); A6 += bflo(w0.w); A7 += bfhi(w0.w);
        B0 += bflo(w1.x); B1 += bfhi(w1.x); B2 += bflo(w1.y); B3 += bfhi(w1.y);
        B4 += bflo(w1.z); B5 += bfhi(w1.z); B6 += bflo(w1.w); B7 += bfhi(w1.w);
        A0 += bflo(w2.x); A1 += bfhi(w2.x); A2 += bflo(w2.y); A3 += bfhi(w2.y);
        A4 += bflo(w2.z); A5 += bfhi(w2.z); A6 += bflo(w2.w); A7 += bfhi(w2.w);
        B0 += bflo(w3.x); B1 += bfhi(w3.x); B2 += bflo(w3.y); B3 += bfhi(w3.y);
        B4 += bflo(w3.z); B5 += bfhi(w3.z); B6 += bflo(w3.w); B7 += bfhi(w3.w);
    }
    for (; p < p1; ++p) {
        int s0 = csr[p];
        uint4 w0 = *(const uint4*)(hwb + (size_t)s0 * CLS + l * 8);
        A0 += bflo(w0.x); A1 += bfhi(w0.x); A2 += bflo(w0.y); A3 += bfhi(w0.y);
        A4 += bflo(w0.z); A5 += bfhi(w0.z); A6 += bflo(w0.w); A7 += bfhi(w0.w);
    }
    A0 += B0; A1 += B1; A2 += B2; A3 += B3;
    A4 += B4; A5 += B5; A6 += B6; A7 += B7;

    float4 bb0 = *(const float4*)(b + l * 8);
    float4 bb1 = *(const float4*)(b + l * 8 + 4);
    float v0 = (A0 + bflo(sw.x)) * dd + bb0.x;
    float v1 = (A1 + bfhi(sw.x)) * dd + bb0.y;
    float v2 = (A2 + bflo(sw.y)) * dd + bb0.z;
    float v3 = (A3 + bfhi(sw.y)) * dd + bb0.w;
    float v4 = (A4 + bflo(sw.z)) * dd + bb1.x;
    float v5 = (A5 + bfhi(sw.z)) * dd + bb1.y;
    float v6 = (A6 + bflo(sw.w)) * dd + bb1.z;
    float v7 = (A7 + bfhi(sw.w)) * dd + bb1.w;

    float m = fmaxf(fmaxf(fmaxf(v0, v1), fmaxf(v2, v3)), fmaxf(fmaxf(v4, v5), fmaxf(v6, v7)));
    m = fmaxf(m, __shfl_xor(m, 1));
    m = fmaxf(m, __shfl_xor(m, 2));
    float s = __expf(v0 - m) + __expf(v1 - m) + __expf(v2 - m) + __expf(v3 - m) +
              __expf(v4 - m) + __expf(v5 - m) + __expf(v6 - m) + __expf(v7 - m);
    s += __shfl_xor(s, 1);
    s += __shfl_xor(s, 2);
    float ls = m + __logf(s);
    float4 o0, o1;
    o0.x = v0 - ls; o0.y = v1 - ls; o0.z = v2 - ls; o0.w = v3 - ls;
    o1.x = v4 - ls; o1.y = v5 - ls; o1.z = v6 - ls; o1.w = v7 - ls;
    float* op = out + (size_t)node * CLS + l * 8;
    *(float4*)op = o0;
    *(float4*)(op + 4) = o1;
}

extern "C" void kernel_launch(void* const* d_in, const int* in_sizes, int n_in,
                              void* d_out, int out_size, void* d_ws, size_t ws_size,
                              hipStream_t stream) {
    const float* x  = (const float*)d_in[0];
    const int* edge = (const int*)d_in[1];
    const float* W1 = (const float*)d_in[2];
    const float* b1 = (const float*)d_in[3];
    const float* W2 = (const float*)d_in[4];
    const float* b2 = (const float*)d_in[5];
    float* out = (float*)d_out;

    int N = in_sizes[0] / F_IN;
    int E = in_sizes[1] / 2;
    const int* src = edge;
    const int* dst = edge + E;

    // workspace layout
    int* deg       = (int*)d_ws;                          // N ints (degree counters)
    int* csr       = deg + N;                             // N*CAP ints (fixed windows)
    unsigned char* bufA = (unsigned char*)(csr + (size_t)N * CAP);        // N*64 B fp8 xW1
    unsigned short* y2  = (unsigned short*)(bufA + (size_t)N * HID);      // N*32 bf16

    // zero degree counters (400 KB)
    hipMemsetAsync(deg, 0, (size_t)N * sizeof(int), stream);

    int sB = (E + 2047) / 2048;               // scatter blocks (one 2048-edge chunk each)
    int nstripes16 = (N + 15) >> 4;
    int gB = (nstripes16 + 3) / 4;            // gemm1 blocks (4 stripes each)

    // ---- K1: atomic CSR scatter || gemm1 (independent, static block split) ----
    k_front<<<sB + gB, 256, 0, stream>>>(src, dst, deg, csr, x, W1, bufA, E, N, sB);

    // ---- K2: fused layer-1 aggregation (per-edge rsqrt(deg+1)) + layer-2 transform ----
    k_gather64_w2<<<(N + 31) / 32, 256, 0, stream>>>(deg, csr, bufA, b1, W2, y2, N);

    // ---- K3: layer-2 aggregation + log_softmax ----
    k_gather32_lsm<<<(N + 63) / 64, 256, 0, stream>>>(deg, csr, y2, b2, out, N);
}

// Round 5
// 192.957 us; speedup vs baseline: 1.2730x; 1.2730x over previous
//
#include <hip/hip_runtime.h>

#define F_IN 128
#define HID 64
#define CLS 32
#define BCAP 4096   // per-bucket capacity (128-node buckets, mean 2048 records -> huge headroom)

typedef short v8s __attribute__((ext_vector_type(8)));
typedef float f4 __attribute__((ext_vector_type(4)));
typedef float f2 __attribute__((ext_vector_type(2)));

// ---- helpers ----
__device__ __forceinline__ float bflo(unsigned int w) { return __uint_as_float(w << 16); }
__device__ __forceinline__ float bfhi(unsigned int w) { return __uint_as_float(w & 0xFFFF0000u); }
__device__ __forceinline__ unsigned short f2bf(float f) {
    unsigned int u = __float_as_uint(f);
    u += 0x7FFFu + ((u >> 16) & 1u);
    return (unsigned short)(u >> 16);
}
// single-instruction RNE pack of 2 f32 -> 2 bf16
__device__ __forceinline__ unsigned int pack2(float lo, float hi) {
    unsigned int r;
    asm("v_cvt_pk_bf16_f32 %0, %1, %2" : "=v"(r) : "v"(lo), "v"(hi));
    return r;
}
__device__ __forceinline__ unsigned char f2fp8(float v) {
    return (unsigned char)(__builtin_amdgcn_cvt_pk_fp8_f32(v, v, 0, false) & 0xFF);
}

// ============ K1: FRONT = bucket-scatter (blocks [0,sB), 4096 edges each) || GEMM1 ============
// Buckets of 128 nodes (NB=782): 2x cursor addresses + half the chunk count vs round-3
// -> ~4x shorter per-cursor atomic RMW chains. Records append contiguously into bucket
// windows (full-line write combining; avoids round-4's 16x write amplification).
// GEMM1 stores UNNORMALIZED fp8 (dinv applied per-edge in the gather).
__global__ __launch_bounds__(256) void k_front(const int* __restrict__ src,
                                               const int* __restrict__ dst,
                                               int* __restrict__ bC,
                                               int* __restrict__ bucketed,
                                               const float* __restrict__ x,
                                               const float* __restrict__ W1,
                                               unsigned char* __restrict__ y,
                                               int E, int nb, int n, int sB) {
    __shared__ union {
        struct { int h[1024]; int chunk[1024]; } sc;
        unsigned short w1[HID * 136];
    } S;
    int tid = threadIdx.x;
    int bid = blockIdx.x;

    if (bid < sB) {
        // ---- bucket scatter: chunk = bid (4096 edges, 16 per thread) ----
        for (int i = tid; i < nb; i += 256) S.sc.h[i] = 0;
        __syncthreads();
        int e0 = bid << 12;
        int myRec[16], myB[16], myRank[16];
#pragma unroll
        for (int k = 0; k < 16; ++k) {
            int e = e0 + k * 256 + tid;
            if (e < E) {
                int d = dst[e];
                myB[k] = d >> 7;
                myRec[k] = src[e] | ((d & 127) << 17);
                myRank[k] = atomicAdd(&S.sc.h[myB[k]], 1);
            } else {
                myB[k] = -1;
            }
        }
        __syncthreads();
        for (int i = tid; i < nb; i += 256)
            S.sc.chunk[i] = S.sc.h[i] ? (i * BCAP + atomicAdd(&bC[i], S.sc.h[i])) : 0;
        __syncthreads();
#pragma unroll
        for (int k = 0; k < 16; ++k)
            if (myB[k] >= 0) bucketed[S.sc.chunk[myB[k]] + myRank[k]] = myRec[k];
    } else {
        // ---- GEMM1: x[N,128] @ W1[128,64] -> fp8 y[N,64] (unnormalized) ----
        for (int i = tid; i < F_IN * HID; i += 256) {
            int k = i >> 6, nn = i & 63;
            S.w1[nn * 136 + k] = f2bf(W1[i]);
        }
        __syncthreads();
        int lane = tid & 63;
        int quad = lane >> 4, c = lane & 15;
        int nstripes = (n + 15) >> 4;
        int stripe = (bid - sB) * 4 + (tid >> 6);
        if (stripe >= nstripes) return;
        int row0 = stripe << 4;

        f4 acc[4] = {};
        union { unsigned int u[4]; v8s v; } au;
#pragma unroll
        for (int ks = 0; ks < 4; ++ks) {
            int k0 = ks * 32 + quad * 8;
            int row = row0 + c;
            if (row >= n) row = n - 1;
            const float* xp = x + (size_t)row * F_IN + k0;
            float4 lo = *(const float4*)xp;
            float4 hi = *(const float4*)(xp + 4);
            au.u[0] = pack2(lo.x, lo.y);
            au.u[1] = pack2(lo.z, lo.w);
            au.u[2] = pack2(hi.x, hi.y);
            au.u[3] = pack2(hi.z, hi.w);
            v8s a = au.v;
#pragma unroll
            for (int nt = 0; nt < 4; ++nt) {
                v8s bb = *(const v8s*)&S.w1[(nt * 16 + c) * 136 + k0];
                acc[nt] = __builtin_amdgcn_mfma_f32_16x16x32_bf16(a, bb, acc[nt], 0, 0, 0);
            }
        }
#pragma unroll
        for (int reg = 0; reg < 4; ++reg) {
            int row = row0 + quad * 4 + reg;
            if (row < n) {
#pragma unroll
                for (int nt = 0; nt < 4; ++nt)
                    y[(size_t)row * HID + nt * 16 + c] = f2fp8(acc[nt][reg]);
            }
        }
    }
}

// ============ K2: per-bucket CSR (512 threads, 128-node buckets), single pass ============
// Per-node windows rounded up to 4 ints -> 16B-aligned, enabling int4 index loads in gathers.
// pk[node] = csr_offset | (cnt << 22); dinv[node] = rsqrt(cnt+1).
__global__ __launch_bounds__(512) void k_csr(const int* __restrict__ bC,
                                             const int* __restrict__ bucketed,
                                             int* __restrict__ pk,
                                             float* __restrict__ dinv, int* __restrict__ csr,
                                             int n) {
    __shared__ int cnt[128];
    __shared__ int s[128];
    __shared__ int baseS[128];
    int b = blockIdx.x;
    int node0 = b << 7;
    int tid = threadIdx.x;
    if (tid < 128) cnt[tid] = 0;
    __syncthreads();
    int nrec = bC[b];
    if (nrec > BCAP) nrec = BCAP;
    int p0 = b * BCAP, p1 = p0 + nrec;

    int rec[8], rnk[8];
#pragma unroll
    for (int k = 0; k < 8; ++k) {
        int p = p0 + tid + (k << 9);
        if (p < p1) {
            int r = bucketed[p];
            rec[k] = r;
            rnk[k] = atomicAdd(&cnt[r >> 17], 1);
        } else {
            rec[k] = -1;
        }
    }
    __syncthreads();
    int v = 0, pv = 0;
    if (tid < 128) { v = cnt[tid]; pv = (v + 3) & ~3; s[tid] = pv; }
    __syncthreads();
    for (int off = 1; off < 128; off <<= 1) {
        int t = (tid >= off && tid < 128) ? s[tid - off] : 0;
        __syncthreads();
        if (tid < 128) s[tid] += t;
        __syncthreads();
    }
    if (tid < 128) {
        int myoff = p0 + s[tid] - pv;      // multiple of 4 -> 16B-aligned window
        baseS[tid] = myoff;
        int node = node0 + tid;
        if (node < n) {
            pk[node] = myoff | (v << 22);
            dinv[node] = rsqrtf((float)(v + 1));
        }
    }
    __syncthreads();
#pragma unroll
    for (int k = 0; k < 8; ++k) {
        if (rec[k] >= 0) csr[baseS[rec[k] >> 17] + rnk[k]] = rec[k] & 0x1FFFF;
    }
}

// ============ K3: gather64 (fp8, per-edge dinv[src]) + bias + relu + W2 -> bf16 y2 ============
// 8 lanes per node; int4 neighbor-index loads (windows 16B-aligned); h tile in LDS,
// then the proven gemm2 MFMA fragment pattern on the LDS tile.
__global__ __launch_bounds__(256) void k_gather64_w2(const int* __restrict__ pk,
                                                     const int* __restrict__ csr,
                                                     const unsigned char* __restrict__ xw8,
                                                     const float* __restrict__ b1,
                                                     const float* __restrict__ W2,
                                                     const float* __restrict__ dinv,
                                                     unsigned short* __restrict__ y2, int n) {
    __shared__ unsigned short Wt[CLS * 72];   // W2 staged as [n][k], padded
    __shared__ unsigned short Hl[32 * 72];    // relu(h) tile, bf16, padded rows
    int tid = threadIdx.x;
    for (int i = tid; i < HID * CLS; i += 256) {
        int k = i >> 5, nn = i & 31;
        Wt[nn * 72 + k] = f2bf(W2[i]);
    }
    // (Wt only read after the barrier below -> no extra barrier needed)

    int g = tid >> 3;                 // local node 0..31
    int l = tid & 7;                  // fp8 cols 8l..8l+7
    int node = blockIdx.x * 32 + g;

    if (node < n) {
        unsigned int pv = (unsigned int)pk[node];
        int p0 = pv & 0x3FFFFF;
        int cntv = (int)(pv >> 22);
        int p1 = p0 + cntv;
        float dd = dinv[node];
        uint2 sw = *(const uint2*)(xw8 + (size_t)node * HID + l * 8);

        f2 a0 = {0.f, 0.f}, a1 = a0, a2 = a0, a3 = a0;
        f2 c0 = a0, c1 = a0, c2 = a0, c3 = a0;
        int q = p0;
        for (; q + 3 < p1; q += 4) {
            int4 ss = *(const int4*)(csr + q);
            float d0 = dinv[ss.x], d1 = dinv[ss.y], d2 = dinv[ss.z], d3 = dinv[ss.w];
            uint2 w0 = *(const uint2*)(xw8 + (size_t)ss.x * HID + l * 8);
            uint2 w1 = *(const uint2*)(xw8 + (size_t)ss.y * HID + l * 8);
            uint2 w2 = *(const uint2*)(xw8 + (size_t)ss.z * HID + l * 8);
            uint2 w3 = *(const uint2*)(xw8 + (size_t)ss.w * HID + l * 8);
            f2 D0 = {d0, d0}, D1 = {d1, d1}, D2 = {d2, d2}, D3 = {d3, d3};
            a0 += __builtin_amdgcn_cvt_pk_f32_fp8(w0.x, false) * D0;
            a1 += __builtin_amdgcn_cvt_pk_f32_fp8(w0.x, true) * D0;
            a2 += __builtin_amdgcn_cvt_pk_f32_fp8(w0.y, false) * D0;
            a3 += __builtin_amdgcn_cvt_pk_f32_fp8(w0.y, true) * D0;
            c0 += __builtin_amdgcn_cvt_pk_f32_fp8(w1.x, false) * D1;
            c1 += __builtin_amdgcn_cvt_pk_f32_fp8(w1.x, true) * D1;
            c2 += __builtin_amdgcn_cvt_pk_f32_fp8(w1.y, false) * D1;
            c3 += __builtin_amdgcn_cvt_pk_f32_fp8(w1.y, true) * D1;
            a0 += __builtin_amdgcn_cvt_pk_f32_fp8(w2.x, false) * D2;
            a1 += __builtin_amdgcn_cvt_pk_f32_fp8(w2.x, true) * D2;
            a2 += __builtin_amdgcn_cvt_pk_f32_fp8(w2.y, false) * D2;
            a3 += __builtin_amdgcn_cvt_pk_f32_fp8(w2.y, true) * D2;
            c0 += __builtin_amdgcn_cvt_pk_f32_fp8(w3.x, false) * D3;
            c1 += __builtin_amdgcn_cvt_pk_f32_fp8(w3.x, true) * D3;
            c2 += __builtin_amdgcn_cvt_pk_f32_fp8(w3.y, false) * D3;
            c3 += __builtin_amdgcn_cvt_pk_f32_fp8(w3.y, true) * D3;
        }
        for (; q < p1; ++q) {
            int s0 = csr[q];
            float d0 = dinv[s0];
            uint2 w0 = *(const uint2*)(xw8 + (size_t)s0 * HID + l * 8);
            f2 D0 = {d0, d0};
            a0 += __builtin_amdgcn_cvt_pk_f32_fp8(w0.x, false) * D0;
            a1 += __builtin_amdgcn_cvt_pk_f32_fp8(w0.x, true) * D0;
            a2 += __builtin_amdgcn_cvt_pk_f32_fp8(w0.y, false) * D0;
            a3 += __builtin_amdgcn_cvt_pk_f32_fp8(w0.y, true) * D0;
        }
        a0 += c0; a1 += c1; a2 += c2; a3 += c3;
        f2 DS = {dd, dd};
        a0 += __builtin_amdgcn_cvt_pk_f32_fp8(sw.x, false) * DS;
        a1 += __builtin_amdgcn_cvt_pk_f32_fp8(sw.x, true) * DS;
        a2 += __builtin_amdgcn_cvt_pk_f32_fp8(sw.y, false) * DS;
        a3 += __builtin_amdgcn_cvt_pk_f32_fp8(sw.y, true) * DS;

        float4 bb0 = *(const float4*)(b1 + l * 8);
        float4 bb1 = *(const float4*)(b1 + l * 8 + 4);
        float h0 = fmaxf(a0.x * dd + bb0.x, 0.f);
        float h1 = fmaxf(a0.y * dd + bb0.y, 0.f);
        float h2 = fmaxf(a1.x * dd + bb0.z, 0.f);
        float h3 = fmaxf(a1.y * dd + bb0.w, 0.f);
        float h4 = fmaxf(a2.x * dd + bb1.x, 0.f);
        float h5 = fmaxf(a2.y * dd + bb1.y, 0.f);
        float h6 = fmaxf(a3.x * dd + bb1.z, 0.f);
        float h7 = fmaxf(a3.y * dd + bb1.w, 0.f);
        uint4 hp;
        hp.x = pack2(h0, h1);
        hp.y = pack2(h2, h3);
        hp.z = pack2(h4, h5);
        hp.w = pack2(h6, h7);
        *(uint4*)&Hl[g * 72 + l * 8] = hp;
    }
    __syncthreads();

    // ---- MFMA epilogue: 4 waves, wave wv handles row-tile t=wv&1, col-tile nt=wv>>1 ----
    int wv = tid >> 6;
    int t = wv & 1, nt = wv >> 1;
    int lane = tid & 63, quad = lane >> 4, c = lane & 15;
    f4 acc = {};
#pragma unroll
    for (int ks = 0; ks < 2; ++ks) {
        int k0 = ks * 32 + quad * 8;
        v8s aF = *(const v8s*)&Hl[(t * 16 + c) * 72 + k0];
        v8s bF = *(const v8s*)&Wt[(nt * 16 + c) * 72 + k0];
        acc = __builtin_amdgcn_mfma_f32_16x16x32_bf16(aF, bF, acc, 0, 0, 0);
    }
    int row0 = blockIdx.x * 32 + t * 16;
#pragma unroll
    for (int reg = 0; reg < 4; ++reg) {
        int row = row0 + quad * 4 + reg;
        if (row < n) {
            float dd2 = dinv[row];
            y2[(size_t)row * CLS + nt * 16 + c] = f2bf(acc[reg] * dd2);
        }
    }
}

// ============ K4: gather width 32 (bf16 rows) + log_softmax: 4 lanes/node, uint4 loads ====
__global__ __launch_bounds__(256) void k_gather32_lsm(const int* __restrict__ pk,
                                                      const int* __restrict__ csr,
                                                      const unsigned short* __restrict__ hwb,
                                                      const float* __restrict__ b,
                                                      const float* __restrict__ dinv,
                                                      float* __restrict__ out, int n) {
    int tid = threadIdx.x;
    int node = blockIdx.x * 64 + (tid >> 2);
    if (node >= n) return;
    int l = tid & 3;    // bf16 cols 8l..8l+7
    unsigned int pv = (unsigned int)pk[node];
    int p0 = pv & 0x3FFFFF;
    int cntv = (int)(pv >> 22);
    int p1 = p0 + cntv;
    float dd = dinv[node];
    uint4 sw = *(const uint4*)(hwb + (size_t)node * CLS + l * 8);

    float A0 = 0.f, A1 = 0.f, A2 = 0.f, A3 = 0.f, A4 = 0.f, A5 = 0.f, A6 = 0.f, A7 = 0.f;
    float B0 = 0.f, B1 = 0.f, B2 = 0.f, B3 = 0.f, B4 = 0.f, B5 = 0.f, B6 = 0.f, B7 = 0.f;
    int p = p0;
    for (; p + 3 < p1; p += 4) {
        int4 ss = *(const int4*)(csr + p);
        uint4 w0 = *(const uint4*)(hwb + (size_t)ss.x * CLS + l * 8);
        uint4 w1 = *(const uint4*)(hwb + (size_t)ss.y * CLS + l * 8);
        uint4 w2 = *(const uint4*)(hwb + (size_t)ss.z * CLS + l * 8);
        uint4 w3 = *(const uint4*)(hwb + (size_t)ss.w * CLS + l * 8);
        A0 += bflo(w0.x); A1 += bfhi(w0.x); A2 += bflo(w0.y); A3 += bfhi(w0.y);
        A4 += bflo(w0.z); A5 += bfhi(w0.z); A6 += bflo(w0.w); A7 += bfhi(w0.w);
        B0 += bflo(w1.x); B1 += bfhi(w1.x); B2 += bflo(w1.y); B3 += bfhi(w1.y);
        B4 += bflo(w1.z); B5 += bfhi(w1.z); B6 += bflo(w1.w); B7 += bfhi(w1.w);
        A0 += bflo(w2.x); A1 += bfhi(w2.x); A2 += bflo(w2.y); A3 += bfhi(w2.y);
        A4 += bflo(w2.z); A5 += bfhi(w2.z); A6 += bflo(w2.w); A7 += bfhi(w2.w);
        B0 += bflo(w3.x); B1 += bfhi(w3.x); B2 += bflo(w3.y); B3 += bfhi(w3.y);
        B4 += bflo(w3.z); B5 += bfhi(w3.z); B6 += bflo(w3.w); B7 += bfhi(w3.w);
    }
    for (; p < p1; ++p) {
        int s0 = csr[p];
        uint4 w0 = *(const uint4*)(hwb + (size_t)s0 * CLS + l * 8);
        A0 += bflo(w0.x); A1 += bfhi(w0.x); A2 += bflo(w0.y); A3 += bfhi(w0.y);
        A4 += bflo(w0.z); A5 += bfhi(w0.z); A6 += bflo(w0.w); A7 += bfhi(w0.w);
    }
    A0 += B0; A1 += B1; A2 += B2; A3 += B3;
    A4 += B4; A5 += B5; A6 += B6; A7 += B7;

    float4 bb0 = *(const float4*)(b + l * 8);
    float4 bb1 = *(const float4*)(b + l * 8 + 4);
    float v0 = (A0 + bflo(sw.x)) * dd + bb0.x;
    float v1 = (A1 + bfhi(sw.x)) * dd + bb0.y;
    float v2 = (A2 + bflo(sw.y)) * dd + bb0.z;
    float v3 = (A3 + bfhi(sw.y)) * dd + bb0.w;
    float v4 = (A4 + bflo(sw.z)) * dd + bb1.x;
    float v5 = (A5 + bfhi(sw.z)) * dd + bb1.y;
    float v6 = (A6 + bflo(sw.w)) * dd + bb1.z;
    float v7 = (A7 + bfhi(sw.w)) * dd + bb1.w;

    float m = fmaxf(fmaxf(fmaxf(v0, v1), fmaxf(v2, v3)), fmaxf(fmaxf(v4, v5), fmaxf(v6, v7)));
    m = fmaxf(m, __shfl_xor(m, 1));
    m = fmaxf(m, __shfl_xor(m, 2));
    float s = __expf(v0 - m) + __expf(v1 - m) + __expf(v2 - m) + __expf(v3 - m) +
              __expf(v4 - m) + __expf(v5 - m) + __expf(v6 - m) + __expf(v7 - m);
    s += __shfl_xor(s, 1);
    s += __shfl_xor(s, 2);
    float ls = m + __logf(s);
    float4 o0, o1;
    o0.x = v0 - ls; o0.y = v1 - ls; o0.z = v2 - ls; o0.w = v3 - ls;
    o1.x = v4 - ls; o1.y = v5 - ls; o1.z = v6 - ls; o1.w = v7 - ls;
    float* op = out + (size_t)node * CLS + l * 8;
    *(float4*)op = o0;
    *(float4*)(op + 4) = o1;
}

extern "C" void kernel_launch(void* const* d_in, const int* in_sizes, int n_in,
                              void* d_out, int out_size, void* d_ws, size_t ws_size,
                              hipStream_t stream) {
    const float* x  = (const float*)d_in[0];
    const int* edge = (const int*)d_in[1];
    const float* W1 = (const float*)d_in[2];
    const float* b1 = (const float*)d_in[3];
    const float* W2 = (const float*)d_in[4];
    const float* b2 = (const float*)d_in[5];
    float* out = (float*)d_out;

    int N = in_sizes[0] / F_IN;
    int E = in_sizes[1] / 2;
    const int* src = edge;
    const int* dst = edge + E;
    int NB = (N + 127) >> 7;   // 782 buckets of 128 nodes

    // workspace layout
    float* dinv    = (float*)d_ws;                        // N f32
    int* pk        = (int*)(dinv + N);                    // N (off | cnt<<22)
    int* bC        = pk + N;                              // 1024 (delta cursors)
    int* csr       = bC + 1024;                           // NB*BCAP (windowed, 4-aligned per node)
    int* bucketed  = csr + (size_t)NB * BCAP;             // NB*BCAP (windowed)
    unsigned char* bufA = (unsigned char*)(bucketed + (size_t)NB * BCAP);  // N*64 B fp8 xW1
    unsigned short* y2  = (unsigned short*)(bufA + (size_t)N * HID);       // N*32 bf16

    // zero delta-cursors (3.1 KB)
    hipMemsetAsync(bC, 0, (size_t)NB * sizeof(int), stream);

    int sB = (E + 4095) / 4096;               // scatter blocks (one 4096-edge chunk each)
    int nstripes16 = (N + 15) >> 4;
    int gB = (nstripes16 + 3) / 4;            // gemm1 blocks (4 stripes each)

    // ---- K1: scatter || gemm1 (independent, static block split) ----
    k_front<<<sB + gB, 256, 0, stream>>>(src, dst, bC, bucketed, x, W1, bufA, E, NB, N, sB);

    // ---- K2: CSR build + dinv ----
    k_csr<<<NB, 512, 0, stream>>>(bC, bucketed, pk, dinv, csr, N);

    // ---- K3: fused layer-1 aggregation (per-edge dinv) + layer-2 transform ----
    k_gather64_w2<<<(N + 31) / 32, 256, 0, stream>>>(pk, csr, bufA, b1, W2, dinv, y2, N);

    // ---- K4: layer-2 aggregation + log_softmax ----
    k_gather32_lsm<<<(N + 63) / 64, 256, 0, stream>>>(pk, csr, y2, b2, dinv, out, N);
}